// Round 8
// baseline (319.014 us; speedup 1.0000x reference)
//
#include <hip/hip_runtime.h>

#define HID 128
#define NEG_SLOPE 0.01f
#define NB 256          // row buckets
#define CHUNK 2048      // edges per block in bucket pass (8/thread)
#define MAX_RB 512      // max rows per bucket (mcons <= 131072)

typedef __attribute__((ext_vector_type(8))) short short8;
typedef __attribute__((ext_vector_type(4))) float f32x4;

__device__ inline unsigned short f2bfu(float f) {
    unsigned u = __float_as_uint(f);
    u += 0x7fff + ((u >> 16) & 1);          // round-to-nearest-even
    return (unsigned short)(u >> 16);
}
__device__ inline float bf2f_lo(unsigned x) { return __uint_as_float((x & 0xffffu) << 16); }
__device__ inline float bf2f_hi(unsigned x) { return __uint_as_float(x & 0xffff0000u); }

#define MFMA16(accv, av, bv) \
    asm("v_mfma_f32_16x16x32_bf16 %0, %1, %2, %0" : "+v"(accv) : "v"(av), "v"(bv))

// ---------------- K0: pack weights to bf16. Wcat[n][k] = bf16(k<128 ? W2[n][k] : -W3[n][k-128]);
__global__ __launch_bounds__(256) void k_prep(
    const float* __restrict__ W1, const float* __restrict__ W2, const float* __restrict__ W3,
    unsigned short* __restrict__ Wcat, unsigned short* __restrict__ W1b)
{
    int gid = blockIdx.x * 256 + threadIdx.x;
    if (gid < 128 * 256) {
        int n = gid >> 8, k = gid & 255;
        float v = (k < 128) ? W2[n * 128 + k] : -W3[n * 128 + (k - 128)];
        Wcat[gid] = f2bfu(v);
    } else {
        int g = gid - 128 * 256;
        W1b[g] = f2bfu(W1[g]);
    }
}

// ---------------- K1: Xb = bf16( [primal|lastp] @ Wcat^T + (b2-b3) )
// R8: hoisted 16-deep A loads (as R7) but min-waves=2 (no VGPR cap spills) and
// araw->af conversion BEFORE the barrier (shortens araw lifetime; overlaps vmcnt wait).
__global__ __launch_bounds__(256, 2) void k_theta_mfma(
    const float* __restrict__ primal, const float* __restrict__ lastp,
    const short8* __restrict__ Wcat,          // [128][256] bf16 = [128][32] short8
    const float* __restrict__ b2, const float* __restrict__ b3,
    unsigned short* __restrict__ Xb, int nvars)
{
    __shared__ short8 Blds[2048];             // 32 KB: one K-half in fragment order
    const int t = threadIdx.x;
    const int l = t & 63, wv = t >> 6;
    const long mbase = (long)blockIdx.x * 128;

    const f32x4 z = {0.f, 0.f, 0.f, 0.f};
    const float4 z4 = {0.f, 0.f, 0.f, 0.f};
    f32x4 acc[2][8];
    #pragma unroll
    for (int rg = 0; rg < 2; ++rg)
        #pragma unroll
        for (int nb = 0; nb < 8; ++nb) acc[rg][nb] = z;

    #pragma unroll 1
    for (int half = 0; half < 2; ++half) {
        if (half) __syncthreads();            // Blds reuse guard (before new ds_writes)

        const float* Ap = half ? lastp : primal;
        // ---- hoisted A loads: 16 independent dwordx4 in flight ----
        float4 araw[2][8];
        #pragma unroll
        for (int rg = 0; rg < 2; ++rg) {
            long row = mbase + wv * 32 + rg * 16 + (l & 15);
            const float4* rp = (const float4*)(Ap + row * HID + ((l >> 4) << 3));
            if (row < nvars) {
                #pragma unroll
                for (int ks = 0; ks < 4; ++ks) {
                    araw[rg][ks * 2 + 0] = rp[ks * 8 + 0];
                    araw[rg][ks * 2 + 1] = rp[ks * 8 + 1];
                }
            } else {
                #pragma unroll
                for (int u = 0; u < 8; ++u) araw[rg][u] = z4;
            }
        }

        // ---- stage B-half into LDS (fragment order), overlaps with A-load latency ----
        #pragma unroll
        for (int i = 0; i < 8; ++i) {
            int e = t + i * 256;
            int lane = e & 63, ks = (e >> 6) & 3, nb = e >> 8;
            int row = nb * 16 + (lane & 15);
            int col8 = (half * 128 + ks * 32 + ((lane >> 4) << 3)) >> 3;
            Blds[e] = Wcat[row * 32 + col8];
        }

        // ---- convert A to bf16 fragments (waits vmcnt; araw dies here) ----
        short8 af[2][4];
        #pragma unroll
        for (int rg = 0; rg < 2; ++rg)
            #pragma unroll
            for (int ks = 0; ks < 4; ++ks) {
                float4 x0 = araw[rg][ks * 2 + 0], x1 = araw[rg][ks * 2 + 1];
                af[rg][ks][0] = (short)f2bfu(x0.x); af[rg][ks][1] = (short)f2bfu(x0.y);
                af[rg][ks][2] = (short)f2bfu(x0.z); af[rg][ks][3] = (short)f2bfu(x0.w);
                af[rg][ks][4] = (short)f2bfu(x1.x); af[rg][ks][5] = (short)f2bfu(x1.y);
                af[rg][ks][6] = (short)f2bfu(x1.z); af[rg][ks][7] = (short)f2bfu(x1.w);
            }

        __syncthreads();

        #pragma unroll
        for (int ks = 0; ks < 4; ++ks) {
            #pragma unroll
            for (int nb = 0; nb < 8; ++nb) {
                short8 bv = Blds[(nb * 4 + ks) * 64 + l];
                MFMA16(acc[0][nb], af[0][ks], bv);
                MFMA16(acc[1][nb], af[1][ks], bv);
            }
        }
    }
    asm volatile("s_nop 7\ns_nop 7");          // MFMA->VALU read hazard insurance

    // C/D: col = l&15, row = (l>>4)*4 + q
    #pragma unroll
    for (int nb = 0; nb < 8; ++nb) {
        int col = nb * 16 + (l & 15);
        float bb = b2[col] - b3[col];
        #pragma unroll
        for (int rg = 0; rg < 2; ++rg) {
            #pragma unroll
            for (int q = 0; q < 4; ++q) {
                long row = mbase + wv * 32 + rg * 16 + ((l >> 4) * 4 + q);
                if (row < nvars) Xb[row * HID + col] = f2bfu(acc[rg][nb][q] + bb);
            }
        }
    }
}

// ---------------- bucket pass A: global bucket histogram
__global__ __launch_bounds__(256) void k_bhist(
    const int* __restrict__ rows, int* __restrict__ bucket_count, int nnz, int rb)
{
    __shared__ int hist[NB];
    int t = threadIdx.x;
    hist[t] = 0; __syncthreads();
    long cbase = (long)blockIdx.x * CHUNK;
    #pragma unroll
    for (int i = 0; i < 8; ++i) {
        long e = cbase + i * 256 + t;
        if (e < nnz) atomicAdd(&hist[rows[e] / rb], 1);
    }
    __syncthreads();
    if (hist[t]) atomicAdd(&bucket_count[t], hist[t]);
}

// ---------------- bucket pass B: scan bucket sizes
__global__ void k_bscan(const int* __restrict__ bucket_count,
                        int* __restrict__ bucket_base, int* __restrict__ bucket_cursor)
{
    if (threadIdx.x == 0 && blockIdx.x == 0) {
        int run = 0;
        for (int i = 0; i < NB; ++i) {
            bucket_base[i] = run; bucket_cursor[i] = run; run += bucket_count[i];
        }
        bucket_base[NB] = run;
    }
}

// ---------------- bucket pass C: bin edges into bucket-contiguous tmp arrays.
__global__ __launch_bounds__(256) void k_bfill(
    const int* __restrict__ rows, const int* __restrict__ cols, const float* __restrict__ vals,
    int* __restrict__ bucket_cursor, int2* __restrict__ tmp_rc, float* __restrict__ tmp_v,
    int nnz, int rb)
{
    __shared__ int hist[NB];
    __shared__ int base[NB];
    int t = threadIdx.x;
    long cbase = (long)blockIdx.x * CHUNK;
    hist[t] = 0;
    __syncthreads();

    int r[8], c[8], b[8], loc[8];
    float v[8];
    #pragma unroll
    for (int i = 0; i < 8; ++i) {
        long e = cbase + i * 256 + t;
        int locv = -1; int bi = 0; int ri = 0, ci = 0; float vi = 0.f;
        if (e < nnz) {
            ri = rows[e]; ci = cols[e]; vi = vals[e];
            bi = ri / rb;
            locv = atomicAdd(&hist[bi], 1);
        }
        r[i] = ri; c[i] = ci; v[i] = vi; b[i] = bi; loc[i] = locv;
    }
    __syncthreads();
    if (hist[t] > 0) base[t] = atomicAdd(&bucket_cursor[t], hist[t]);
    __syncthreads();
    #pragma unroll
    for (int i = 0; i < 8; ++i) {
        if (loc[i] >= 0) {
            int slot = base[b[i]] + loc[i];
            tmp_rc[slot] = make_int2(r[i], c[i]);
            tmp_v[slot]  = v[i];
        }
    }
}

// ---------------- bucket pass D: one block per bucket -> local CSR + pairs.
__global__ __launch_bounds__(256) void k_csr(
    const int2* __restrict__ tmp_rc, const float* __restrict__ tmp_v,
    const int* __restrict__ bucket_base,
    int* __restrict__ rowstart, int* __restrict__ count, int2* __restrict__ pairs,
    int m, int rb)
{
    __shared__ int cnt[MAX_RB];
    __shared__ int cur[MAX_RB];
    int b = blockIdx.x, t = threadIdx.x;
    int row0 = b * rb;
    int nrows = m - row0; if (nrows > rb) nrows = rb;
    if (nrows <= 0) return;

    for (int i = t; i < nrows; i += 256) cnt[i] = 0;
    __syncthreads();

    int e0 = bucket_base[b], e1 = bucket_base[b + 1];
    for (int e = e0 + t; e < e1; e += 256)
        atomicAdd(&cnt[tmp_rc[e].x - row0], 1);
    __syncthreads();

    if (t == 0) {
        int run = e0;
        for (int i = 0; i < nrows; ++i) { cur[i] = run; run += cnt[i]; }
    }
    __syncthreads();

    for (int i = t; i < nrows; i += 256) {
        rowstart[row0 + i] = cur[i];
        count[row0 + i]    = cnt[i];
    }
    __syncthreads();

    for (int e = e0 + t; e < e1; e += 256) {
        int2 rc = tmp_rc[e];
        float vv = tmp_v[e];
        int slot = atomicAdd(&cur[rc.x - row0], 1);
        pairs[slot] = make_int2(rc.y, __float_as_int(vv));
    }
}

// ---------------- K3: out[r,:] = sigma * sum_j val_j * X[col_j,:]   (one wave per row, unroll-4)
__global__ __launch_bounds__(256) void k_segsum(
    const int2* __restrict__ pairs, const int* __restrict__ rowstart, const int* __restrict__ count,
    const unsigned short* __restrict__ Xb, const float* __restrict__ sigp,
    float* __restrict__ out, int m)
{
    int wid = (blockIdx.x * 256 + threadIdx.x) >> 6;
    if (wid >= m) return;
    int lane = threadIdx.x & 63;
    int start = rowstart[wid];
    int cnt   = count[wid];
    const unsigned short* xb = Xb + lane * 2;

    float a0 = 0.f, a1 = 0.f;
    int j = 0;
    for (; j + 4 <= cnt; j += 4) {
        int2 p0 = pairs[start + j + 0];
        int2 p1 = pairs[start + j + 1];
        int2 p2 = pairs[start + j + 2];
        int2 p3 = pairs[start + j + 3];
        unsigned x0 = *(const unsigned*)(xb + (size_t)p0.x * HID);
        unsigned x1 = *(const unsigned*)(xb + (size_t)p1.x * HID);
        unsigned x2 = *(const unsigned*)(xb + (size_t)p2.x * HID);
        unsigned x3 = *(const unsigned*)(xb + (size_t)p3.x * HID);
        float v0 = __int_as_float(p0.y), v1 = __int_as_float(p1.y);
        float v2 = __int_as_float(p2.y), v3 = __int_as_float(p3.y);
        a0 += v0 * bf2f_lo(x0); a1 += v0 * bf2f_hi(x0);
        a0 += v1 * bf2f_lo(x1); a1 += v1 * bf2f_hi(x1);
        a0 += v2 * bf2f_lo(x2); a1 += v2 * bf2f_hi(x2);
        a0 += v3 * bf2f_lo(x3); a1 += v3 * bf2f_hi(x3);
    }
    for (; j < cnt; ++j) {
        int2 p = pairs[start + j];
        float v = __int_as_float(p.y);
        unsigned x = *(const unsigned*)(xb + (size_t)p.x * HID);
        a0 += v * bf2f_lo(x);
        a1 += v * bf2f_hi(x);
    }
    float sg = *sigp;
    ((float2*)out)[(size_t)wid * 64 + lane] = make_float2(sg * a0, sg * a1);
}

// ---------------- K4: out = leaky_relu(dual @ W1^T + b1 + out - sigma*rhs)
// R8: hoisted loads + early conversion, min-waves=2.
__global__ __launch_bounds__(256, 2) void k_dual_mfma(
    const float* __restrict__ dual,
    const short8* __restrict__ W1b,           // [128][128] bf16 = [128][16] short8
    const float* __restrict__ b1, const float* __restrict__ rhs,
    const float* __restrict__ sigp, float* __restrict__ out, int mcons)
{
    __shared__ short8 Blds[2048];
    const int t = threadIdx.x;
    const int l = t & 63, wv = t >> 6;
    const long mbase = (long)blockIdx.x * 128;
    const float sigma = *sigp;
    const float4 z4 = {0.f, 0.f, 0.f, 0.f};

    const f32x4 z = {0.f, 0.f, 0.f, 0.f};
    f32x4 acc[2][8];
    #pragma unroll
    for (int rg = 0; rg < 2; ++rg)
        #pragma unroll
        for (int nb = 0; nb < 8; ++nb) acc[rg][nb] = z;

    // ---- hoisted A loads ----
    float4 araw[2][8];
    #pragma unroll
    for (int rg = 0; rg < 2; ++rg) {
        long row = mbase + wv * 32 + rg * 16 + (l & 15);
        const float4* rp = (const float4*)(dual + row * HID + ((l >> 4) << 3));
        if (row < mcons) {
            #pragma unroll
            for (int ks = 0; ks < 4; ++ks) {
                araw[rg][ks * 2 + 0] = rp[ks * 8 + 0];
                araw[rg][ks * 2 + 1] = rp[ks * 8 + 1];
            }
        } else {
            #pragma unroll
            for (int u = 0; u < 8; ++u) araw[rg][u] = z4;
        }
    }

    // ---- stage W1 into LDS (fragment order) ----
    #pragma unroll
    for (int i = 0; i < 8; ++i) {
        int e = t + i * 256;
        int lane = e & 63, ks = (e >> 6) & 3, nb = e >> 8;
        int row = nb * 16 + (lane & 15);
        int col8 = (ks * 32 + ((lane >> 4) << 3)) >> 3;
        Blds[e] = W1b[row * 16 + col8];
    }

    // ---- convert (waits vmcnt; araw dies) ----
    short8 af[2][4];
    #pragma unroll
    for (int rg = 0; rg < 2; ++rg)
        #pragma unroll
        for (int ks = 0; ks < 4; ++ks) {
            float4 x0 = araw[rg][ks * 2 + 0], x1 = araw[rg][ks * 2 + 1];
            af[rg][ks][0] = (short)f2bfu(x0.x); af[rg][ks][1] = (short)f2bfu(x0.y);
            af[rg][ks][2] = (short)f2bfu(x0.z); af[rg][ks][3] = (short)f2bfu(x0.w);
            af[rg][ks][4] = (short)f2bfu(x1.x); af[rg][ks][5] = (short)f2bfu(x1.y);
            af[rg][ks][6] = (short)f2bfu(x1.z); af[rg][ks][7] = (short)f2bfu(x1.w);
        }

    __syncthreads();

    #pragma unroll
    for (int ks = 0; ks < 4; ++ks) {
        #pragma unroll
        for (int nb = 0; nb < 8; ++nb) {
            short8 bv = Blds[(nb * 4 + ks) * 64 + l];
            MFMA16(acc[0][nb], af[0][ks], bv);
            MFMA16(acc[1][nb], af[1][ks], bv);
        }
    }
    asm volatile("s_nop 7\ns_nop 7");

    #pragma unroll
    for (int nb = 0; nb < 8; ++nb) {
        int col = nb * 16 + (l & 15);
        float bb = b1[col];
        #pragma unroll
        for (int rg = 0; rg < 2; ++rg) {
            #pragma unroll
            for (int q = 0; q < 4; ++q) {
                long row = mbase + wv * 32 + rg * 16 + ((l >> 4) * 4 + q);
                if (row < mcons) {
                    long idx = row * HID + col;
                    float pre = acc[rg][nb][q] + bb + out[idx] - sigma * rhs[idx];
                    out[idx] = (pre >= 0.f) ? pre : NEG_SLOPE * pre;
                }
            }
        }
    }
}

extern "C" void kernel_launch(void* const* d_in, const int* in_sizes, int n_in,
                              void* d_out, int out_size, void* d_ws, size_t ws_size,
                              hipStream_t stream) {
    const float* primal = (const float*)d_in[0];
    const float* lastp  = (const float*)d_in[1];
    const float* dual   = (const float*)d_in[2];
    const int*   rows   = (const int*)d_in[3];
    const int*   cols   = (const int*)d_in[4];
    const float* vals   = (const float*)d_in[5];
    const float* rhs    = (const float*)d_in[6];
    const float* W1     = (const float*)d_in[7];
    const float* b1     = (const float*)d_in[8];
    const float* W2     = (const float*)d_in[9];
    const float* b2     = (const float*)d_in[10];
    const float* W3     = (const float*)d_in[11];
    const float* b3     = (const float*)d_in[12];
    const float* sigp   = (const float*)d_in[13];

    const int nvars = in_sizes[0] / HID;   // 200000
    const int mcons = in_sizes[2] / HID;   // 100000
    const int nnz   = in_sizes[3];         // 1600000
    const int rb    = (mcons + NB - 1) / NB;   // rows per bucket (391)

    float* out = (float*)d_out;

    // ---- workspace layout ----
    char* wsb = (char*)d_ws;
    unsigned short* Xb   = (unsigned short*)wsb;                        // 51.2 MB bf16
    size_t off = (size_t)nvars * HID * sizeof(unsigned short);
    int2* pairs   = (int2*)(wsb + off);  off += (size_t)nnz * sizeof(int2);   // 12.8 MB
    int2* tmp_rc  = (int2*)(wsb + off);  off += (size_t)nnz * sizeof(int2);   // 12.8 MB
    float* tmp_v  = (float*)(wsb + off); off += (size_t)nnz * sizeof(float);  //  6.4 MB
    unsigned short* Wcat = (unsigned short*)(wsb + off); off += 128 * 256 * 2;
    unsigned short* W1b  = (unsigned short*)(wsb + off); off += 128 * 128 * 2;
    int* count         = (int*)(wsb + off); off += (size_t)mcons * sizeof(int);
    int* rowstart      = (int*)(wsb + off); off += (size_t)mcons * sizeof(int);
    int* bucket_count  = (int*)(wsb + off); off += NB * sizeof(int);
    int* bucket_base   = (int*)(wsb + off); off += (NB + 1) * sizeof(int);
    int* bucket_cursor = (int*)(wsb + off); off += NB * sizeof(int);

    hipMemsetAsync(bucket_count, 0, NB * sizeof(int), stream);

    k_prep<<<192, 256, 0, stream>>>(W1, W2, W3, Wcat, W1b);

    const int nchunk_blocks = (nnz + CHUNK - 1) / CHUNK;
    k_bhist<<<nchunk_blocks, 256, 0, stream>>>(rows, bucket_count, nnz, rb);
    k_bscan<<<1, 64, 0, stream>>>(bucket_count, bucket_base, bucket_cursor);
    k_bfill<<<nchunk_blocks, 256, 0, stream>>>(rows, cols, vals, bucket_cursor,
                                               tmp_rc, tmp_v, nnz, rb);
    k_csr<<<NB, 256, 0, stream>>>(tmp_rc, tmp_v, bucket_base,
                                  rowstart, count, pairs, mcons, rb);

    k_theta_mfma<<<(nvars + 127) / 128, 256, 0, stream>>>(
        primal, lastp, (const short8*)Wcat, b2, b3, Xb, nvars);

    k_segsum<<<(mcons * 64 + 255) / 256, 256, 0, stream>>>(
        pairs, rowstart, count, Xb, sigp, out, mcons);

    k_dual_mfma<<<(mcons + 127) / 128, 256, 0, stream>>>(
        dual, (const short8*)W1b, b1, rhs, sigp, out, mcons);
}

// Round 9
// 282.652 us; speedup vs baseline: 1.1286x; 1.1286x over previous
//
#include <hip/hip_runtime.h>

#define HID 128
#define NEG_SLOPE 0.01f
#define NB 256          // row buckets
#define CHUNK 2048      // edges per block in bucket pass (8/thread)
#define MAX_RB 512      // max rows per bucket (mcons <= 131072)

typedef __attribute__((ext_vector_type(8))) short short8;
typedef __attribute__((ext_vector_type(4))) float f32x4;
typedef __attribute__((ext_vector_type(4))) unsigned u32x4;

__device__ inline unsigned short f2bfu(float f) {
    unsigned u = __float_as_uint(f);
    u += 0x7fff + ((u >> 16) & 1);          // round-to-nearest-even
    return (unsigned short)(u >> 16);
}
__device__ inline float bf2f_lo(unsigned x) { return __uint_as_float((x & 0xffffu) << 16); }
__device__ inline float bf2f_hi(unsigned x) { return __uint_as_float(x & 0xffff0000u); }

__device__ inline unsigned cvtpk(float lo, float hi) {
    unsigned r;
    asm("v_cvt_pk_bf16_f32 %0, %1, %2" : "=v"(r) : "v"(lo), "v"(hi));
    return r;
}

// swapped-operand MFMA: W-fragment as A (M=hid), X-row-fragment as B (N=rows)
#define MFMA_SW(accv, wfrag, xfrag) \
    asm("v_mfma_f32_16x16x32_bf16 %0, %1, %2, %0" : "+v"(accv) : "v"(wfrag), "v"(xfrag))

// ---------------- K0: pack weights to bf16 (B^T layout = torch layout)
__global__ __launch_bounds__(256) void k_prep(
    const float* __restrict__ W1, const float* __restrict__ W2, const float* __restrict__ W3,
    unsigned short* __restrict__ Wcat, unsigned short* __restrict__ W1b)
{
    int gid = blockIdx.x * 256 + threadIdx.x;
    if (gid < 128 * 256) {
        int n = gid >> 8, k = gid & 255;
        float v = (k < 128) ? W2[n * 128 + k] : -W3[n * 128 + (k - 128)];
        Wcat[gid] = f2bfu(v);
    } else {
        int g = gid - 128 * 256;
        W1b[g] = f2bfu(W1[g]);
    }
}

// ---- helpers for the MFMA kernels ----
__device__ inline void load_a(const float* __restrict__ Ap, long tile, int nrows_tot,
                              int rrow, int rcol, float4 (&araw)[2][8])
{
    const float4 z4 = {0.f, 0.f, 0.f, 0.f};
    #pragma unroll
    for (int rg = 0; rg < 2; ++rg) {
        long row = tile * 128 + rrow + rg * 16;
        const float4* rp = (const float4*)(Ap + row * HID + rcol);
        if (row < nrows_tot) {
            #pragma unroll
            for (int ks = 0; ks < 4; ++ks) {
                araw[rg][ks * 2 + 0] = rp[ks * 8 + 0];
                araw[rg][ks * 2 + 1] = rp[ks * 8 + 1];
            }
        } else {
            #pragma unroll
            for (int u = 0; u < 8; ++u) araw[rg][u] = z4;
        }
    }
}

__device__ inline void conv_a(const float4 (&araw)[2][8], u32x4 (&af)[2][4])
{
    #pragma unroll
    for (int rg = 0; rg < 2; ++rg)
        #pragma unroll
        for (int ks = 0; ks < 4; ++ks) {
            float4 x0 = araw[rg][ks * 2 + 0], x1 = araw[rg][ks * 2 + 1];
            af[rg][ks][0] = cvtpk(x0.x, x0.y);
            af[rg][ks][1] = cvtpk(x0.z, x0.w);
            af[rg][ks][2] = cvtpk(x1.x, x1.y);
            af[rg][ks][3] = cvtpk(x1.z, x1.w);
        }
}

__device__ inline void mfma_half(f32x4 (&acc)[2][8], const u32x4 (&af)[2][4],
                                 const short8* Blds, int base, int l)
{
    #pragma unroll
    for (int ks = 0; ks < 4; ++ks)
        #pragma unroll
        for (int nb = 0; nb < 8; ++nb) {
            short8 bv = Blds[base + (nb * 4 + ks) * 64 + l];
            MFMA_SW(acc[0][nb], bv, af[0][ks]);
            MFMA_SW(acc[1][nb], bv, af[1][ks]);
        }
}

// ---------------- K1: Xb = bf16( [primal|lastp] @ Wcat^T + (b2-b3) )
// R9: cross-tile software pipeline (grid-stride), both W halves in 64KB LDS,
// swapped operands (per-lane output = 4 consecutive cols of one row), cvt_pk.
__global__ __launch_bounds__(256, 2) void k_theta_mfma(
    const float* __restrict__ primal, const float* __restrict__ lastp,
    const short8* __restrict__ Wcat,          // [128][256] bf16 = [128][32] short8
    const float* __restrict__ b2, const float* __restrict__ b3,
    unsigned short* __restrict__ Xb, int nvars, int ntiles, int gridsz)
{
    __shared__ short8 Blds[4096];             // 64 KB: both K-halves, fragment order
    const int t = threadIdx.x;
    const int l = t & 63, wv = t >> 6;
    const int rrow = wv * 32 + (l & 15);      // + rg*16 -> row within tile
    const int rcol = (l >> 4) << 3;           // k-offset base (floats)
    const int colb = (l >> 4) << 2;           // output col base within nb-group

    // prologue: issue first tile's primal loads (in flight during staging)
    float4 araw[2][8];
    const long tile0 = blockIdx.x;
    load_a(primal, tile0, nvars, rrow, rcol, araw);

    // stage both W halves: entry e = half*2048 + (nb*4+ks)*64 + lane
    #pragma unroll
    for (int i = 0; i < 16; ++i) {
        int e = t + i * 256;
        int lane = e & 63, ks = (e >> 6) & 3, nb = (e >> 8) & 7, hf = e >> 11;
        int row = nb * 16 + (lane & 15);
        int col8 = (hf * 128 + ks * 32 + ((lane >> 4) << 3)) >> 3;
        Blds[e] = Wcat[row * 32 + col8];
    }

    // per-lane bias (b2-b3) for cols nb*16 + colb .. +3
    float4 bias[8];
    #pragma unroll
    for (int nb = 0; nb < 8; ++nb) {
        int col = nb * 16 + colb;
        float4 p = *(const float4*)&b2[col];
        float4 q = *(const float4*)&b3[col];
        bias[nb] = make_float4(p.x - q.x, p.y - q.y, p.z - q.z, p.w - q.w);
    }

    __syncthreads();

    const f32x4 z = {0.f, 0.f, 0.f, 0.f};
    f32x4 acc[2][8];
    #pragma unroll
    for (int rg = 0; rg < 2; ++rg)
        #pragma unroll
        for (int nb = 0; nb < 8; ++nb) acc[rg][nb] = z;

    u32x4 af[2][4];

    #pragma unroll 1
    for (long tile = tile0; tile < ntiles; tile += gridsz) {
        // half 0 (primal): loads already in flight
        conv_a(araw, af);                                  // waits vmcnt
        load_a(lastp, tile, nvars, rrow, rcol, araw);      // issue half-1 loads
        mfma_half(acc, af, Blds, 0, l);                    // hide under MFMA

        // half 1 (lastp)
        conv_a(araw, af);
        long nt = tile + gridsz;
        if (nt < ntiles) load_a(primal, nt, nvars, rrow, rcol, araw);  // next-tile prefetch
        mfma_half(acc, af, Blds, 2048, l);

        asm volatile("s_nop 7\ns_nop 7");                  // MFMA->VALU hazard insurance
        // epilogue: lane holds rows (rrow+rg*16), cols nb*16+colb..+3 (consecutive)
        #pragma unroll
        for (int rg = 0; rg < 2; ++rg) {
            long row = tile * 128 + rrow + rg * 16;
            if (row < nvars) {
                #pragma unroll
                for (int nb = 0; nb < 8; ++nb) {
                    uint2 w;
                    w.x = cvtpk(acc[rg][nb][0] + bias[nb].x, acc[rg][nb][1] + bias[nb].y);
                    w.y = cvtpk(acc[rg][nb][2] + bias[nb].z, acc[rg][nb][3] + bias[nb].w);
                    *(uint2*)&Xb[row * HID + nb * 16 + colb] = w;
                }
            }
            #pragma unroll
            for (int nb = 0; nb < 8; ++nb) acc[rg][nb] = z;
        }
    }
}

// ---------------- bucket pass A: global bucket histogram
__global__ __launch_bounds__(256) void k_bhist(
    const int* __restrict__ rows, int* __restrict__ bucket_count, int nnz, int rb)
{
    __shared__ int hist[NB];
    int t = threadIdx.x;
    hist[t] = 0; __syncthreads();
    long cbase = (long)blockIdx.x * CHUNK;
    #pragma unroll
    for (int i = 0; i < 8; ++i) {
        long e = cbase + i * 256 + t;
        if (e < nnz) atomicAdd(&hist[rows[e] / rb], 1);
    }
    __syncthreads();
    if (hist[t]) atomicAdd(&bucket_count[t], hist[t]);
}

// ---------------- bucket pass B: scan bucket sizes
__global__ void k_bscan(const int* __restrict__ bucket_count,
                        int* __restrict__ bucket_base, int* __restrict__ bucket_cursor)
{
    if (threadIdx.x == 0 && blockIdx.x == 0) {
        int run = 0;
        for (int i = 0; i < NB; ++i) {
            bucket_base[i] = run; bucket_cursor[i] = run; run += bucket_count[i];
        }
        bucket_base[NB] = run;
    }
}

// ---------------- bucket pass C: bin edges into bucket-contiguous tmp arrays.
__global__ __launch_bounds__(256) void k_bfill(
    const int* __restrict__ rows, const int* __restrict__ cols, const float* __restrict__ vals,
    int* __restrict__ bucket_cursor, int2* __restrict__ tmp_rc, float* __restrict__ tmp_v,
    int nnz, int rb)
{
    __shared__ int hist[NB];
    __shared__ int base[NB];
    int t = threadIdx.x;
    long cbase = (long)blockIdx.x * CHUNK;
    hist[t] = 0;
    __syncthreads();

    int r[8], c[8], b[8], loc[8];
    float v[8];
    #pragma unroll
    for (int i = 0; i < 8; ++i) {
        long e = cbase + i * 256 + t;
        int locv = -1; int bi = 0; int ri = 0, ci = 0; float vi = 0.f;
        if (e < nnz) {
            ri = rows[e]; ci = cols[e]; vi = vals[e];
            bi = ri / rb;
            locv = atomicAdd(&hist[bi], 1);
        }
        r[i] = ri; c[i] = ci; v[i] = vi; b[i] = bi; loc[i] = locv;
    }
    __syncthreads();
    if (hist[t] > 0) base[t] = atomicAdd(&bucket_cursor[t], hist[t]);
    __syncthreads();
    #pragma unroll
    for (int i = 0; i < 8; ++i) {
        if (loc[i] >= 0) {
            int slot = base[b[i]] + loc[i];
            tmp_rc[slot] = make_int2(r[i], c[i]);
            tmp_v[slot]  = v[i];
        }
    }
}

// ---------------- bucket pass D: one block per bucket -> local CSR + pairs.
__global__ __launch_bounds__(256) void k_csr(
    const int2* __restrict__ tmp_rc, const float* __restrict__ tmp_v,
    const int* __restrict__ bucket_base,
    int* __restrict__ rowstart, int* __restrict__ count, int2* __restrict__ pairs,
    int m, int rb)
{
    __shared__ int cnt[MAX_RB];
    __shared__ int cur[MAX_RB];
    int b = blockIdx.x, t = threadIdx.x;
    int row0 = b * rb;
    int nrows = m - row0; if (nrows > rb) nrows = rb;
    if (nrows <= 0) return;

    for (int i = t; i < nrows; i += 256) cnt[i] = 0;
    __syncthreads();

    int e0 = bucket_base[b], e1 = bucket_base[b + 1];
    for (int e = e0 + t; e < e1; e += 256)
        atomicAdd(&cnt[tmp_rc[e].x - row0], 1);
    __syncthreads();

    if (t == 0) {
        int run = e0;
        for (int i = 0; i < nrows; ++i) { cur[i] = run; run += cnt[i]; }
    }
    __syncthreads();

    for (int i = t; i < nrows; i += 256) {
        rowstart[row0 + i] = cur[i];
        count[row0 + i]    = cnt[i];
    }
    __syncthreads();

    for (int e = e0 + t; e < e1; e += 256) {
        int2 rc = tmp_rc[e];
        float vv = tmp_v[e];
        int slot = atomicAdd(&cur[rc.x - row0], 1);
        pairs[slot] = make_int2(rc.y, __float_as_int(vv));
    }
}

// ---------------- K3: out[r,:] = sigma * sum_j val_j * X[col_j,:]  (one wave/row, unroll-8)
__global__ __launch_bounds__(256) void k_segsum(
    const int2* __restrict__ pairs, const int* __restrict__ rowstart, const int* __restrict__ count,
    const unsigned short* __restrict__ Xb, const float* __restrict__ sigp,
    float* __restrict__ out, int m)
{
    int wid = (blockIdx.x * 256 + threadIdx.x) >> 6;
    if (wid >= m) return;
    int lane = threadIdx.x & 63;
    int start = rowstart[wid];
    int cnt   = count[wid];
    const unsigned short* xb = Xb + lane * 2;

    float a0 = 0.f, a1 = 0.f;
    int j = 0;
    for (; j + 8 <= cnt; j += 8) {
        int2 p[8]; unsigned x[8];
        #pragma unroll
        for (int u = 0; u < 8; ++u) p[u] = pairs[start + j + u];
        #pragma unroll
        for (int u = 0; u < 8; ++u) x[u] = *(const unsigned*)(xb + (size_t)p[u].x * HID);
        #pragma unroll
        for (int u = 0; u < 8; ++u) {
            float v = __int_as_float(p[u].y);
            a0 += v * bf2f_lo(x[u]);
            a1 += v * bf2f_hi(x[u]);
        }
    }
    for (; j + 4 <= cnt; j += 4) {
        int2 p[4]; unsigned x[4];
        #pragma unroll
        for (int u = 0; u < 4; ++u) p[u] = pairs[start + j + u];
        #pragma unroll
        for (int u = 0; u < 4; ++u) x[u] = *(const unsigned*)(xb + (size_t)p[u].x * HID);
        #pragma unroll
        for (int u = 0; u < 4; ++u) {
            float v = __int_as_float(p[u].y);
            a0 += v * bf2f_lo(x[u]);
            a1 += v * bf2f_hi(x[u]);
        }
    }
    for (; j < cnt; ++j) {
        int2 p = pairs[start + j];
        float v = __int_as_float(p.y);
        unsigned x = *(const unsigned*)(xb + (size_t)p.x * HID);
        a0 += v * bf2f_lo(x);
        a1 += v * bf2f_hi(x);
    }
    float sg = *sigp;
    ((float2*)out)[(size_t)wid * 64 + lane] = make_float2(sg * a0, sg * a1);
}

// ---------------- K4: out = leaky_relu(dual @ W1^T + b1 + out - sigma*rhs)
// R9: swapped operands -> float4 out/rhs epilogue; cvt_pk conversions.
__global__ __launch_bounds__(256, 2) void k_dual_mfma(
    const float* __restrict__ dual,
    const short8* __restrict__ W1b,           // [128][128] bf16 = [128][16] short8
    const float* __restrict__ b1, const float* __restrict__ rhs,
    const float* __restrict__ sigp, float* __restrict__ out, int mcons)
{
    __shared__ short8 Blds[2048];
    const int t = threadIdx.x;
    const int l = t & 63, wv = t >> 6;
    const int rrow = wv * 32 + (l & 15);
    const int rcol = (l >> 4) << 3;
    const int colb = (l >> 4) << 2;
    const float sigma = *sigp;

    // hoisted A loads (dual rows for this block's tile)
    float4 araw[2][8];
    load_a(dual, blockIdx.x, mcons, rrow, rcol, araw);

    // stage W1 (fragment order, 2048 entries)
    #pragma unroll
    for (int i = 0; i < 8; ++i) {
        int e = t + i * 256;
        int lane = e & 63, ks = (e >> 6) & 3, nb = e >> 8;
        int row = nb * 16 + (lane & 15);
        int col8 = (ks * 32 + ((lane >> 4) << 3)) >> 3;
        Blds[e] = W1b[row * 16 + col8];
    }

    float4 bias[8];
    #pragma unroll
    for (int nb = 0; nb < 8; ++nb)
        bias[nb] = *(const float4*)&b1[nb * 16 + colb];

    u32x4 af[2][4];
    conv_a(araw, af);

    __syncthreads();

    const f32x4 z = {0.f, 0.f, 0.f, 0.f};
    f32x4 acc[2][8];
    #pragma unroll
    for (int rg = 0; rg < 2; ++rg)
        #pragma unroll
        for (int nb = 0; nb < 8; ++nb) acc[rg][nb] = z;

    mfma_half(acc, af, Blds, 0, l);
    asm volatile("s_nop 7\ns_nop 7");

    #pragma unroll
    for (int rg = 0; rg < 2; ++rg) {
        long row = (long)blockIdx.x * 128 + rrow + rg * 16;
        if (row < mcons) {
            #pragma unroll
            for (int nb = 0; nb < 8; ++nb) {
                long idx = row * HID + nb * 16 + colb;
                float4 o = *(const float4*)&out[idx];
                float4 r = *(const float4*)&rhs[idx];
                float4 pre;
                pre.x = acc[rg][nb][0] + bias[nb].x + o.x - sigma * r.x;
                pre.y = acc[rg][nb][1] + bias[nb].y + o.y - sigma * r.y;
                pre.z = acc[rg][nb][2] + bias[nb].z + o.z - sigma * r.z;
                pre.w = acc[rg][nb][3] + bias[nb].w + o.w - sigma * r.w;
                pre.x = (pre.x >= 0.f) ? pre.x : NEG_SLOPE * pre.x;
                pre.y = (pre.y >= 0.f) ? pre.y : NEG_SLOPE * pre.y;
                pre.z = (pre.z >= 0.f) ? pre.z : NEG_SLOPE * pre.z;
                pre.w = (pre.w >= 0.f) ? pre.w : NEG_SLOPE * pre.w;
                *(float4*)&out[idx] = pre;
            }
        }
    }
}

extern "C" void kernel_launch(void* const* d_in, const int* in_sizes, int n_in,
                              void* d_out, int out_size, void* d_ws, size_t ws_size,
                              hipStream_t stream) {
    const float* primal = (const float*)d_in[0];
    const float* lastp  = (const float*)d_in[1];
    const float* dual   = (const float*)d_in[2];
    const int*   rows   = (const int*)d_in[3];
    const int*   cols   = (const int*)d_in[4];
    const float* vals   = (const float*)d_in[5];
    const float* rhs    = (const float*)d_in[6];
    const float* W1     = (const float*)d_in[7];
    const float* b1     = (const float*)d_in[8];
    const float* W2     = (const float*)d_in[9];
    const float* b2     = (const float*)d_in[10];
    const float* W3     = (const float*)d_in[11];
    const float* b3     = (const float*)d_in[12];
    const float* sigp   = (const float*)d_in[13];

    const int nvars = in_sizes[0] / HID;   // 200000
    const int mcons = in_sizes[2] / HID;   // 100000
    const int nnz   = in_sizes[3];         // 1600000
    const int rb    = (mcons + NB - 1) / NB;   // rows per bucket (391)

    float* out = (float*)d_out;

    // ---- workspace layout ----
    char* wsb = (char*)d_ws;
    unsigned short* Xb   = (unsigned short*)wsb;                        // 51.2 MB bf16
    size_t off = (size_t)nvars * HID * sizeof(unsigned short);
    int2* pairs   = (int2*)(wsb + off);  off += (size_t)nnz * sizeof(int2);   // 12.8 MB
    int2* tmp_rc  = (int2*)(wsb + off);  off += (size_t)nnz * sizeof(int2);   // 12.8 MB
    float* tmp_v  = (float*)(wsb + off); off += (size_t)nnz * sizeof(float);  //  6.4 MB
    unsigned short* Wcat = (unsigned short*)(wsb + off); off += 128 * 256 * 2;
    unsigned short* W1b  = (unsigned short*)(wsb + off); off += 128 * 128 * 2;
    int* count         = (int*)(wsb + off); off += (size_t)mcons * sizeof(int);
    int* rowstart      = (int*)(wsb + off); off += (size_t)mcons * sizeof(int);
    int* bucket_count  = (int*)(wsb + off); off += NB * sizeof(int);
    int* bucket_base   = (int*)(wsb + off); off += (NB + 1) * sizeof(int);
    int* bucket_cursor = (int*)(wsb + off); off += NB * sizeof(int);

    hipMemsetAsync(bucket_count, 0, NB * sizeof(int), stream);

    k_prep<<<192, 256, 0, stream>>>(W1, W2, W3, Wcat, W1b);

    const int nchunk_blocks = (nnz + CHUNK - 1) / CHUNK;
    k_bhist<<<nchunk_blocks, 256, 0, stream>>>(rows, bucket_count, nnz, rb);
    k_bscan<<<1, 64, 0, stream>>>(bucket_count, bucket_base, bucket_cursor);
    k_bfill<<<nchunk_blocks, 256, 0, stream>>>(rows, cols, vals, bucket_cursor,
                                               tmp_rc, tmp_v, nnz, rb);
    k_csr<<<NB, 256, 0, stream>>>(tmp_rc, tmp_v, bucket_base,
                                  rowstart, count, pairs, mcons, rb);

    const int ntiles = (nvars + 127) / 128;                 // 1563
    int gridsz = 512; if (gridsz > ntiles) gridsz = ntiles; // 2 blocks/CU (64KB LDS)
    k_theta_mfma<<<gridsz, 256, 0, stream>>>(
        primal, lastp, (const short8*)Wcat, b2, b3, Xb, nvars, ntiles, gridsz);

    k_segsum<<<(mcons * 64 + 255) / 256, 256, 0, stream>>>(
        pairs, rowstart, count, Xb, sigp, out, mcons);

    k_dual_mfma<<<(mcons + 127) / 128, 256, 0, stream>>>(
        dual, (const short8*)W1b, b1, rhs, sigp, out, mcons);
}